// Round 2
// baseline (231.483 us; speedup 1.0000x reference)
//
#include <hip/hip_runtime.h>
#include <hip/hip_bf16.h>

#define T_TOK 8192
#define DDIM 1024
#define HDIM 1024
#define NEXP 8
#define KTOP 2
#define NROWS (T_TOK * KTOP)

typedef __attribute__((ext_vector_type(8))) short bf16x8;
typedef __attribute__((ext_vector_type(4))) float f32x4;

__device__ __forceinline__ unsigned short f2bf(float f) {
    unsigned u = __builtin_bit_cast(unsigned, f);
    u += 0x7fffu + ((u >> 16) & 1u);   // RNE
    return (unsigned short)(u >> 16);
}
__device__ __forceinline__ float bf2f(unsigned short h) {
    return __builtin_bit_cast(float, (unsigned)h << 16);
}

// async global->LDS, 16B per lane. LDS dest must be wave-uniform base;
// HW writes lane i at base + i*16. Global src is per-lane (gather-safe).
__device__ __forceinline__ void gll16(const unsigned short* g, const unsigned short* l) {
    __builtin_amdgcn_global_load_lds(
        (const __attribute__((address_space(1))) unsigned int*)g,
        (__attribute__((address_space(3))) unsigned int*)l, 16, 0, 0);
}

// ---------------- prep kernels ----------------

__global__ __launch_bounds__(256) void cvt_bf16_k(const float* __restrict__ in,
                                                  unsigned short* __restrict__ out, int n4) {
    int i = blockIdx.x * 256 + threadIdx.x;
    if (i >= n4) return;
    float4 v = ((const float4*)in)[i];
    ushort4 o;
    o.x = f2bf(v.x); o.y = f2bf(v.y); o.z = f2bf(v.z); o.w = f2bf(v.w);
    ((ushort4*)out)[i] = o;
}

// in: [nmat][R][C] f32  ->  out: [nmat][C][R] bf16
__global__ __launch_bounds__(256) void transpose_cast_k(const float* __restrict__ in,
                                                        unsigned short* __restrict__ out,
                                                        int R, int C) {
    __shared__ unsigned short tile[32][33];
    int m = blockIdx.z;
    const float* src = in + (size_t)m * R * C;
    unsigned short* dst = out + (size_t)m * R * C;
    int c0 = blockIdx.x * 32, r0 = blockIdx.y * 32;
    int tx = threadIdx.x & 31, ty = threadIdx.x >> 5;
#pragma unroll
    for (int i = 0; i < 32; i += 8)
        tile[ty + i][tx] = f2bf(src[(size_t)(r0 + ty + i) * C + c0 + tx]);
    __syncthreads();
#pragma unroll
    for (int i = 0; i < 32; i += 8)
        dst[(size_t)(c0 + ty + i) * R + r0 + tx] = tile[tx][ty + i];
}

// ---------------- GEMM: C = act(A @ B^T + bias) ----------------
// A: bf16 rows (optionally gathered via rowidx), lda elements per row
// Bt: [E][N][K] bf16 (B transposed), biasE: [E][N] f32
// VARIANT 0: Out[r][c] = bf16(acc + bias)
// VARIANT 1: Out[r][c] = bf16(silu(Gin[r][c]) * (acc + bias))

constexpr int BM = 128, BN = 128, BK = 64;

template <int VARIANT>
__global__ __launch_bounds__(256) void gemm_bt_k(
    const unsigned short* __restrict__ A, const int* __restrict__ rowidx, int lda,
    const unsigned short* __restrict__ Bt, const float* __restrict__ biasE,
    const unsigned short* __restrict__ Gin, unsigned short* __restrict__ Out,
    const int* __restrict__ offsets, int N, int K) {
    // linear (unpadded) LDS: required by global_load_lds (wave-uniform dest + lane*16)
    __shared__ __align__(16) unsigned short As[BM][BK];
    __shared__ __align__(16) unsigned short Bs[BN][BK];

    const int nbn = N / BN;
    int brow = blockIdx.x / nbn, bcol = blockIdx.x % nbn;
    int row0 = brow * BM, col0 = bcol * BN;
    int e = 0;
    while (offsets[e + 1] <= row0) ++e;   // contiguous expert segments

    const unsigned short* Bte = Bt + (size_t)e * N * K;
    const float* bias = biasE + (size_t)e * N;

    int tid = threadIdx.x;
    int lane = tid & 63, wid = tid >> 6;
    int wr = wid >> 1, wc = wid & 1;      // 2x2 wave grid, 64x64 per wave
    int l15 = lane & 15, l4 = lane >> 4;

    // staging: per issue p, a wave covers 8 rows of 128B; lane i -> row i>>3, bytes (i&7)*16
    int lrow = lane >> 3;                 // 0..7
    int lcol = (lane & 7) * 8;            // bf16 elems (16B)

    const unsigned short* aptr[4];
    const unsigned short* bptr[4];
#pragma unroll
    for (int p = 0; p < 4; ++p) {
        int gr = row0 + p * 32 + wid * 8 + lrow;
        int ar = rowidx ? rowidx[gr] : gr;
        aptr[p] = A + (size_t)ar * lda + lcol;
        bptr[p] = Bte + (size_t)(col0 + p * 32 + wid * 8 + lrow) * K + lcol;
    }

    f32x4 acc[4][4] = {};

    for (int k0 = 0; k0 < K; k0 += BK) {
#pragma unroll
        for (int p = 0; p < 4; ++p) {
            gll16(aptr[p] + k0, &As[p * 32 + wid * 8][0]);
            gll16(bptr[p] + k0, &Bs[p * 32 + wid * 8][0]);
        }
        __syncthreads();                  // compiler drains vmcnt before barrier
#pragma unroll
        for (int kk = 0; kk < BK; kk += 32) {
            bf16x8 af[4], bfr[4];
#pragma unroll
            for (int mi = 0; mi < 4; ++mi)
                af[mi] = *(const bf16x8*)&As[wr * 64 + mi * 16 + l15][kk + l4 * 8];
#pragma unroll
            for (int ni = 0; ni < 4; ++ni)
                bfr[ni] = *(const bf16x8*)&Bs[wc * 64 + ni * 16 + l15][kk + l4 * 8];
#pragma unroll
            for (int mi = 0; mi < 4; ++mi)
#pragma unroll
                for (int ni = 0; ni < 4; ++ni)
                    acc[mi][ni] = __builtin_amdgcn_mfma_f32_16x16x32_bf16(
                        af[mi], bfr[ni], acc[mi][ni], 0, 0, 0);
        }
        __syncthreads();
    }

    float bv[4];
#pragma unroll
    for (int ni = 0; ni < 4; ++ni)
        bv[ni] = bias[col0 + wc * 64 + ni * 16 + l15];

#pragma unroll
    for (int mi = 0; mi < 4; ++mi) {
        int orow_b = row0 + wr * 64 + mi * 16 + l4 * 4;
#pragma unroll
        for (int ni = 0; ni < 4; ++ni) {
            int ocol = col0 + wc * 64 + ni * 16 + l15;
#pragma unroll
            for (int q = 0; q < 4; ++q) {
                size_t oidx = (size_t)(orow_b + q) * N + ocol;
                float v = acc[mi][ni][q] + bv[ni];
                if (VARIANT == 1) {
                    float g = bf2f(Gin[oidx]);
                    float s = g / (1.0f + __expf(-g));
                    v = s * v;
                }
                Out[oidx] = f2bf(v);
            }
        }
    }
}

// ---------------- combine ----------------

__global__ __launch_bounds__(256) void combine_k(
    const unsigned short* __restrict__ Y, const int* __restrict__ rev,
    const float* __restrict__ gates, const int* __restrict__ gidx,
    float* __restrict__ out) {
    int t = blockIdx.x;
    int r0 = rev[2 * t], r1 = rev[2 * t + 1];
    float g0 = gates[gidx[2 * t]], g1 = gates[gidx[2 * t + 1]];
    const unsigned short* y0 = Y + (size_t)r0 * DDIM;
    const unsigned short* y1 = Y + (size_t)r1 * DDIM;
    int d = threadIdx.x * 4;
    ushort4 a = *(const ushort4*)(y0 + d);
    ushort4 b = *(const ushort4*)(y1 + d);
    float4 r;
    r.x = g0 * bf2f(a.x) + g1 * bf2f(b.x);
    r.y = g0 * bf2f(a.y) + g1 * bf2f(b.y);
    r.z = g0 * bf2f(a.z) + g1 * bf2f(b.z);
    r.w = g0 * bf2f(a.w) + g1 * bf2f(b.w);
    *(float4*)(out + (size_t)t * DDIM + d) = r;
}

// ---------------- launch ----------------

extern "C" void kernel_launch(void* const* d_in, const int* in_sizes, int n_in,
                              void* d_out, int out_size, void* d_ws, size_t ws_size,
                              hipStream_t stream) {
    const int* offsets = (const int*)d_in[0];
    const float* jagged = (const float*)d_in[1];
    const float* weight = (const float*)d_in[2];
    const float* bias = (const float*)d_in[3];
    const int* index = (const int*)d_in[4];
    const float* weight_p = (const float*)d_in[5];
    const float* weight_out = (const float*)d_in[6];
    const int* rev = (const int*)d_in[7];
    const float* gates = (const float*)d_in[8];
    const int* gidx = (const int*)d_in[9];
    const float* bias_p = (const float*)d_in[10];
    const float* bias_out = (const float*)d_in[11];
    float* out = (float*)d_out;

    char* w = (char*)d_ws;
    unsigned short* jag_bf = (unsigned short*)w; w += (size_t)T_TOK * DDIM * 2;   // 16MB
    unsigned short* W1t    = (unsigned short*)w; w += (size_t)NEXP * DDIM * HDIM * 2; // 16MB
    unsigned short* Wpt    = (unsigned short*)w; w += (size_t)NEXP * DDIM * HDIM * 2; // 16MB
    unsigned short* Wot    = (unsigned short*)w; w += (size_t)NEXP * HDIM * DDIM * 2; // 16MB
    unsigned short* g_ws   = (unsigned short*)w; w += (size_t)NROWS * HDIM * 2;   // 32MB
    unsigned short* h_ws   = (unsigned short*)w; w += (size_t)NROWS * HDIM * 2;   // 32MB
    unsigned short* y_ws   = g_ws;  // g dead after GEMM-u epilogue; reuse for y

    // prep: bf16 casts + weight transposes (B^T layout for contiguous MFMA frags)
    cvt_bf16_k<<<(T_TOK * DDIM / 4 + 255) / 256, 256, 0, stream>>>(jagged, jag_bf, T_TOK * DDIM / 4);
    transpose_cast_k<<<dim3(HDIM / 32, DDIM / 32, NEXP), 256, 0, stream>>>(weight, W1t, DDIM, HDIM);
    transpose_cast_k<<<dim3(HDIM / 32, DDIM / 32, NEXP), 256, 0, stream>>>(weight_p, Wpt, DDIM, HDIM);
    transpose_cast_k<<<dim3(DDIM / 32, HDIM / 32, NEXP), 256, 0, stream>>>(weight_out, Wot, HDIM, DDIM);

    // g = gather(x) @ W + b
    int grid1 = (NROWS / BM) * (HDIM / BN);
    gemm_bt_k<0><<<grid1, 256, 0, stream>>>(jag_bf, index, DDIM, W1t, bias, nullptr, g_ws,
                                            offsets, HDIM, DDIM);
    // h = silu(g) * (gather(x) @ Wp + bp)
    gemm_bt_k<1><<<grid1, 256, 0, stream>>>(jag_bf, index, DDIM, Wpt, bias_p, g_ws, h_ws,
                                            offsets, HDIM, DDIM);
    // y = h @ Wout + bout
    int grid3 = (NROWS / BM) * (DDIM / BN);
    gemm_bt_k<0><<<grid3, 256, 0, stream>>>(h_ws, nullptr, HDIM, Wot, bias_out, nullptr, y_ws,
                                            offsets, DDIM, HDIM);
    // out[t] = sum_k gates[gidx[t,k]] * y[rev[t,k]]
    combine_k<<<T_TOK, 256, 0, stream>>>(y_ws, rev, gates, gidx, out);
}

// Round 3
// 231.172 us; speedup vs baseline: 1.0013x; 1.0013x over previous
//
#include <hip/hip_runtime.h>
#include <hip/hip_bf16.h>

#define T_TOK 8192
#define DDIM 1024
#define HDIM 1024
#define NEXP 8
#define KTOP 2
#define NROWS (T_TOK * KTOP)

typedef __attribute__((ext_vector_type(8))) short bf16x8;
typedef __attribute__((ext_vector_type(4))) float f32x4;

__device__ __forceinline__ unsigned short f2bf(float f) {
    unsigned u = __builtin_bit_cast(unsigned, f);
    u += 0x7fffu + ((u >> 16) & 1u);   // RNE
    return (unsigned short)(u >> 16);
}
__device__ __forceinline__ float bf2f(unsigned short h) {
    return __builtin_bit_cast(float, (unsigned)h << 16);
}

// ---------------- prep kernels ----------------

__global__ __launch_bounds__(256) void cvt_bf16_k(const float* __restrict__ in,
                                                  unsigned short* __restrict__ out, int n4) {
    int i = blockIdx.x * 256 + threadIdx.x;
    if (i >= n4) return;
    float4 v = ((const float4*)in)[i];
    ushort4 o;
    o.x = f2bf(v.x); o.y = f2bf(v.y); o.z = f2bf(v.z); o.w = f2bf(v.w);
    ((ushort4*)out)[i] = o;
}

// in: [nmat][R][C] f32  ->  out: [nmat][C][R] bf16
__global__ __launch_bounds__(256) void transpose_cast_k(const float* __restrict__ in,
                                                        unsigned short* __restrict__ out,
                                                        int R, int C) {
    __shared__ unsigned short tile[32][33];
    int m = blockIdx.z;
    const float* src = in + (size_t)m * R * C;
    unsigned short* dst = out + (size_t)m * R * C;
    int c0 = blockIdx.x * 32, r0 = blockIdx.y * 32;
    int tx = threadIdx.x & 31, ty = threadIdx.x >> 5;
#pragma unroll
    for (int i = 0; i < 32; i += 8)
        tile[ty + i][tx] = f2bf(src[(size_t)(r0 + ty + i) * C + c0 + tx]);
    __syncthreads();
#pragma unroll
    for (int i = 0; i < 32; i += 8)
        dst[(size_t)(c0 + ty + i) * R + r0 + tx] = tile[tx][ty + i];
}

// ---------------- GEMM common geometry ----------------
// 128x128 tile, BK=64, 4 waves in 2x2 grid (64x64 per wave), padded reg-staged
// LDS (+8 elems = 16B; row stride 144B -> 2-way bank alias only, free per m136).
// XCD swizzle: grid = 8 bcol-chunks x 128 brow; launch idx i -> XCD i%8; remap so
// XCD x owns brows [x*16, x*16+16) = expert x's 2048 rows exactly.

constexpr int BM = 128, BN = 128, BK = 64, LDK = BK + 8;

__device__ __forceinline__ void xcd_block(int nbn, int& brow, int& bcol) {
    int nwg = (NROWS / BM) * nbn;                       // 1024
    int l = (blockIdx.x & 7) * (nwg >> 3) + (blockIdx.x >> 3);
    brow = l / nbn;                                     // brow-major within chunk
    bcol = l % nbn;
}

// ---------------- fused gate+up GEMM ----------------
// h[r][c] = silu(x[r]@W1[:,c] + b1[c]) * (x[r]@W2[:,c] + b2[c]),  x gathered via rowidx

__global__ __launch_bounds__(256) void gemm_fused_k(
    const unsigned short* __restrict__ A, const int* __restrict__ rowidx,
    const unsigned short* __restrict__ B1t, const unsigned short* __restrict__ B2t,
    const float* __restrict__ bias1E, const float* __restrict__ bias2E,
    unsigned short* __restrict__ Out, const int* __restrict__ offsets) {
    const int N = HDIM, K = DDIM, lda = DDIM;
    __shared__ __align__(16) unsigned short As[BM][LDK];
    __shared__ __align__(16) unsigned short B1s[BN][LDK];
    __shared__ __align__(16) unsigned short B2s[BN][LDK];

    int brow, bcol;
    xcd_block(N / BN, brow, bcol);
    int row0 = brow * BM, col0 = bcol * BN;
    int e = 0;
    while (offsets[e + 1] <= row0) ++e;

    const unsigned short* B1e = B1t + (size_t)e * N * K;
    const unsigned short* B2e = B2t + (size_t)e * N * K;
    const float* b1 = bias1E + (size_t)e * N;
    const float* b2 = bias2E + (size_t)e * N;

    int tid = threadIdx.x;
    int lane = tid & 63, wid = tid >> 6;
    int wr = wid >> 1, wc = wid & 1;
    int l15 = lane & 15, l4 = lane >> 4;

    int srr = tid >> 3;                   // 0..31
    int sk8 = (tid & 7) * 8;              // 0..56

    size_t abase[4], bbase[4];
#pragma unroll
    for (int p = 0; p < 4; ++p) {
        int gr = row0 + p * 32 + srr;
        abase[p] = (size_t)rowidx[gr] * lda;
        bbase[p] = (size_t)(col0 + p * 32 + srr) * K;
    }

    f32x4 acc1[4][4] = {};
    f32x4 acc2[4][4] = {};

    for (int k0 = 0; k0 < K; k0 += BK) {
#pragma unroll
        for (int p = 0; p < 4; ++p) {
            *(uint4*)&As[p * 32 + srr][sk8]  = *(const uint4*)(A + abase[p] + k0 + sk8);
            *(uint4*)&B1s[p * 32 + srr][sk8] = *(const uint4*)(B1e + bbase[p] + k0 + sk8);
            *(uint4*)&B2s[p * 32 + srr][sk8] = *(const uint4*)(B2e + bbase[p] + k0 + sk8);
        }
        __syncthreads();
#pragma unroll
        for (int kk = 0; kk < BK; kk += 32) {
            bf16x8 af[4], b1f[4], b2f[4];
#pragma unroll
            for (int mi = 0; mi < 4; ++mi)
                af[mi] = *(const bf16x8*)&As[wr * 64 + mi * 16 + l15][kk + l4 * 8];
#pragma unroll
            for (int ni = 0; ni < 4; ++ni) {
                b1f[ni] = *(const bf16x8*)&B1s[wc * 64 + ni * 16 + l15][kk + l4 * 8];
                b2f[ni] = *(const bf16x8*)&B2s[wc * 64 + ni * 16 + l15][kk + l4 * 8];
            }
#pragma unroll
            for (int mi = 0; mi < 4; ++mi)
#pragma unroll
                for (int ni = 0; ni < 4; ++ni) {
                    acc1[mi][ni] = __builtin_amdgcn_mfma_f32_16x16x32_bf16(
                        af[mi], b1f[ni], acc1[mi][ni], 0, 0, 0);
                    acc2[mi][ni] = __builtin_amdgcn_mfma_f32_16x16x32_bf16(
                        af[mi], b2f[ni], acc2[mi][ni], 0, 0, 0);
                }
        }
        __syncthreads();
    }

    float bv1[4], bv2[4];
#pragma unroll
    for (int ni = 0; ni < 4; ++ni) {
        int c = col0 + wc * 64 + ni * 16 + l15;
        bv1[ni] = b1[c];
        bv2[ni] = b2[c];
    }

#pragma unroll
    for (int mi = 0; mi < 4; ++mi) {
        int orow_b = row0 + wr * 64 + mi * 16 + l4 * 4;
#pragma unroll
        for (int ni = 0; ni < 4; ++ni) {
            int ocol = col0 + wc * 64 + ni * 16 + l15;
#pragma unroll
            for (int q = 0; q < 4; ++q) {
                float g = acc1[mi][ni][q] + bv1[ni];
                float u = acc2[mi][ni][q] + bv2[ni];
                float s = g / (1.0f + __expf(-g));
                Out[(size_t)(orow_b + q) * N + ocol] = f2bf(s * u);
            }
        }
    }
}

// ---------------- plain GEMM (y = h @ Wout^T + bout) ----------------

__global__ __launch_bounds__(256) void gemm_bt_k(
    const unsigned short* __restrict__ A, int lda,
    const unsigned short* __restrict__ Bt, const float* __restrict__ biasE,
    unsigned short* __restrict__ Out, const int* __restrict__ offsets, int N, int K) {
    __shared__ __align__(16) unsigned short As[BM][LDK];
    __shared__ __align__(16) unsigned short Bs[BN][LDK];

    int brow, bcol;
    xcd_block(N / BN, brow, bcol);
    int row0 = brow * BM, col0 = bcol * BN;
    int e = 0;
    while (offsets[e + 1] <= row0) ++e;

    const unsigned short* Bte = Bt + (size_t)e * N * K;
    const float* bias = biasE + (size_t)e * N;

    int tid = threadIdx.x;
    int lane = tid & 63, wid = tid >> 6;
    int wr = wid >> 1, wc = wid & 1;
    int l15 = lane & 15, l4 = lane >> 4;

    int srr = tid >> 3;
    int sk8 = (tid & 7) * 8;

    size_t abase[4], bbase[4];
#pragma unroll
    for (int p = 0; p < 4; ++p) {
        abase[p] = (size_t)(row0 + p * 32 + srr) * lda;
        bbase[p] = (size_t)(col0 + p * 32 + srr) * K;
    }

    f32x4 acc[4][4] = {};

    for (int k0 = 0; k0 < K; k0 += BK) {
#pragma unroll
        for (int p = 0; p < 4; ++p) {
            *(uint4*)&As[p * 32 + srr][sk8] = *(const uint4*)(A + abase[p] + k0 + sk8);
            *(uint4*)&Bs[p * 32 + srr][sk8] = *(const uint4*)(Bte + bbase[p] + k0 + sk8);
        }
        __syncthreads();
#pragma unroll
        for (int kk = 0; kk < BK; kk += 32) {
            bf16x8 af[4], bfr[4];
#pragma unroll
            for (int mi = 0; mi < 4; ++mi)
                af[mi] = *(const bf16x8*)&As[wr * 64 + mi * 16 + l15][kk + l4 * 8];
#pragma unroll
            for (int ni = 0; ni < 4; ++ni)
                bfr[ni] = *(const bf16x8*)&Bs[wc * 64 + ni * 16 + l15][kk + l4 * 8];
#pragma unroll
            for (int mi = 0; mi < 4; ++mi)
#pragma unroll
                for (int ni = 0; ni < 4; ++ni)
                    acc[mi][ni] = __builtin_amdgcn_mfma_f32_16x16x32_bf16(
                        af[mi], bfr[ni], acc[mi][ni], 0, 0, 0);
        }
        __syncthreads();
    }

    float bv[4];
#pragma unroll
    for (int ni = 0; ni < 4; ++ni)
        bv[ni] = bias[col0 + wc * 64 + ni * 16 + l15];

#pragma unroll
    for (int mi = 0; mi < 4; ++mi) {
        int orow_b = row0 + wr * 64 + mi * 16 + l4 * 4;
#pragma unroll
        for (int ni = 0; ni < 4; ++ni) {
            int ocol = col0 + wc * 64 + ni * 16 + l15;
#pragma unroll
            for (int q = 0; q < 4; ++q)
                Out[(size_t)(orow_b + q) * N + ocol] = f2bf(acc[mi][ni][q] + bv[ni]);
        }
    }
}

// ---------------- combine ----------------

__global__ __launch_bounds__(256) void combine_k(
    const unsigned short* __restrict__ Y, const int* __restrict__ rev,
    const float* __restrict__ gates, const int* __restrict__ gidx,
    float* __restrict__ out) {
    int t = blockIdx.x;
    int r0 = rev[2 * t], r1 = rev[2 * t + 1];
    float g0 = gates[gidx[2 * t]], g1 = gates[gidx[2 * t + 1]];
    const unsigned short* y0 = Y + (size_t)r0 * DDIM;
    const unsigned short* y1 = Y + (size_t)r1 * DDIM;
    int d = threadIdx.x * 4;
    ushort4 a = *(const ushort4*)(y0 + d);
    ushort4 b = *(const ushort4*)(y1 + d);
    float4 r;
    r.x = g0 * bf2f(a.x) + g1 * bf2f(b.x);
    r.y = g0 * bf2f(a.y) + g1 * bf2f(b.y);
    r.z = g0 * bf2f(a.z) + g1 * bf2f(b.z);
    r.w = g0 * bf2f(a.w) + g1 * bf2f(b.w);
    *(float4*)(out + (size_t)t * DDIM + d) = r;
}

// ---------------- launch ----------------

extern "C" void kernel_launch(void* const* d_in, const int* in_sizes, int n_in,
                              void* d_out, int out_size, void* d_ws, size_t ws_size,
                              hipStream_t stream) {
    const int* offsets = (const int*)d_in[0];
    const float* jagged = (const float*)d_in[1];
    const float* weight = (const float*)d_in[2];
    const float* bias = (const float*)d_in[3];
    const int* index = (const int*)d_in[4];
    const float* weight_p = (const float*)d_in[5];
    const float* weight_out = (const float*)d_in[6];
    const int* rev = (const int*)d_in[7];
    const float* gates = (const float*)d_in[8];
    const int* gidx = (const int*)d_in[9];
    const float* bias_p = (const float*)d_in[10];
    const float* bias_out = (const float*)d_in[11];
    float* out = (float*)d_out;

    char* w = (char*)d_ws;
    unsigned short* jag_bf = (unsigned short*)w; w += (size_t)T_TOK * DDIM * 2;       // 16MB
    unsigned short* W1t    = (unsigned short*)w; w += (size_t)NEXP * DDIM * HDIM * 2; // 16MB
    unsigned short* Wpt    = (unsigned short*)w; w += (size_t)NEXP * DDIM * HDIM * 2; // 16MB
    unsigned short* Wot    = (unsigned short*)w; w += (size_t)NEXP * HDIM * DDIM * 2; // 16MB
    unsigned short* h_ws   = (unsigned short*)w; w += (size_t)NROWS * HDIM * 2;       // 32MB
    unsigned short* y_ws   = (unsigned short*)w; w += (size_t)NROWS * DDIM * 2;       // 32MB

    // prep: bf16 casts + weight transposes (B^T layout for contiguous MFMA frags)
    cvt_bf16_k<<<(T_TOK * DDIM / 4 + 255) / 256, 256, 0, stream>>>(jagged, jag_bf, T_TOK * DDIM / 4);
    transpose_cast_k<<<dim3(HDIM / 32, DDIM / 32, NEXP), 256, 0, stream>>>(weight, W1t, DDIM, HDIM);
    transpose_cast_k<<<dim3(HDIM / 32, DDIM / 32, NEXP), 256, 0, stream>>>(weight_p, Wpt, DDIM, HDIM);
    transpose_cast_k<<<dim3(DDIM / 32, HDIM / 32, NEXP), 256, 0, stream>>>(weight_out, Wot, HDIM, DDIM);

    // h = silu(gather(x)@W + b) * (gather(x)@Wp + bp)   [fused gate+up]
    int grid1 = (NROWS / BM) * (HDIM / BN);   // 1024
    gemm_fused_k<<<grid1, 256, 0, stream>>>(jag_bf, index, W1t, Wpt, bias, bias_p, h_ws, offsets);

    // y = h @ Wout + bout
    int grid3 = (NROWS / BM) * (DDIM / BN);   // 1024
    gemm_bt_k<<<grid3, 256, 0, stream>>>(h_ws, HDIM, Wot, bias_out, y_ws, offsets, DDIM, HDIM);

    // out[t] = sum_k gates[gidx[t,k]] * y[rev[t,k]]
    combine_k<<<T_TOK, 256, 0, stream>>>(y_ws, rev, gates, gidx, out);
}

// Round 4
// 213.015 us; speedup vs baseline: 1.0867x; 1.0852x over previous
//
#include <hip/hip_runtime.h>
#include <hip/hip_bf16.h>

#define T_TOK 8192
#define DDIM 1024
#define HDIM 1024
#define NEXP 8
#define KTOP 2
#define NROWS (T_TOK * KTOP)

typedef __attribute__((ext_vector_type(8))) short bf16x8;
typedef __attribute__((ext_vector_type(4))) float f32x4;

__device__ __forceinline__ unsigned short f2bf(float f) {
    unsigned u = __builtin_bit_cast(unsigned, f);
    u += 0x7fffu + ((u >> 16) & 1u);   // RNE
    return (unsigned short)(u >> 16);
}
__device__ __forceinline__ float bf2f(unsigned short h) {
    return __builtin_bit_cast(float, (unsigned)h << 16);
}

// async global->LDS, 16B per lane; LDS dest wave-uniform base + lane*16.
__device__ __forceinline__ void gll16(const unsigned short* g, const unsigned short* l) {
    __builtin_amdgcn_global_load_lds(
        (const __attribute__((address_space(1))) unsigned int*)g,
        (__attribute__((address_space(3))) unsigned int*)l, 16, 0, 0);
}

// ---------------- prep kernels ----------------

__global__ __launch_bounds__(256) void cvt_bf16_k(const float* __restrict__ in,
                                                  unsigned short* __restrict__ out, int n4) {
    int i = blockIdx.x * 256 + threadIdx.x;
    if (i >= n4) return;
    float4 v = ((const float4*)in)[i];
    ushort4 o;
    o.x = f2bf(v.x); o.y = f2bf(v.y); o.z = f2bf(v.z); o.w = f2bf(v.w);
    ((ushort4*)out)[i] = o;
}

// in: [nmat][R][C] f32  ->  out: [nmat][C][R] bf16
__global__ __launch_bounds__(256) void transpose_cast_k(const float* __restrict__ in,
                                                        unsigned short* __restrict__ out,
                                                        int R, int C) {
    __shared__ unsigned short tile[32][33];
    int m = blockIdx.z;
    const float* src = in + (size_t)m * R * C;
    unsigned short* dst = out + (size_t)m * R * C;
    int c0 = blockIdx.x * 32, r0 = blockIdx.y * 32;
    int tx = threadIdx.x & 31, ty = threadIdx.x >> 5;
#pragma unroll
    for (int i = 0; i < 32; i += 8)
        tile[ty + i][tx] = f2bf(src[(size_t)(r0 + ty + i) * C + c0 + tx]);
    __syncthreads();
#pragma unroll
    for (int i = 0; i < 32; i += 8)
        dst[(size_t)(c0 + ty + i) * R + r0 + tx] = tile[tx][ty + i];
}

// ---------------- 256x256 GEMM, 2-phase double-buffered (T3-minimum) ------------
// C = act(A @ Bt^T + bias). 512 thr = 8 waves (2Mx4N), per-wave 128x64 out.
// LDS: 2 x (A 256x64 + B 256x64) bf16 = 128 KiB -> 1 block/CU.
// Staging: gll16, linear LDS (dest constraint); prefetch t+1 issued BEFORE
// compute of t; single vmcnt(0)+barrier per K-tile (= __syncthreads).
// T1: XCD-chunked block map -> XCD x owns expert x's rows entirely.
// VARIANT 0: out = acc + bias ;  VARIANT 1: out = silu(Gin) * (acc + bias)

constexpr int BM2 = 256, BN2 = 256, BK2 = 64;
constexpr int NT2 = DDIM / BK2;   // K = 1024 -> 16 K-tiles

template <int VARIANT>
__global__ __launch_bounds__(512) void gemm256_k(
    const unsigned short* __restrict__ A, const int* __restrict__ rowidx, int lda,
    const unsigned short* __restrict__ Bt, const float* __restrict__ biasE,
    const unsigned short* __restrict__ Gin, unsigned short* __restrict__ Out,
    const int* __restrict__ offsets, int N, int K) {
    __shared__ __align__(16) unsigned short As[2][BM2][BK2];
    __shared__ __align__(16) unsigned short Bs[2][BN2][BK2];

    // XCD-chunked map: 256 blocks, 8 XCDs, 32 blocks each; brow-major in chunk.
    const int nbn = N / BN2;                          // 4
    int l = (blockIdx.x & 7) * 32 + (blockIdx.x >> 3);
    int brow = l / nbn, bcol = l % nbn;
    int row0 = brow * BM2, col0 = bcol * BN2;
    int e = 0;
    while (offsets[e + 1] <= row0) ++e;

    const unsigned short* Bte = Bt + (size_t)e * N * K;
    const float* bias = biasE + (size_t)e * N;

    int tid = threadIdx.x;
    int lane = tid & 63, wid = tid >> 6;
    int wm = wid >> 2, wn = wid & 3;                  // 2x4 wave grid
    int l15 = lane & 15, l4 = lane >> 4;

    // staging geometry: issue p covers rows [p*64, +64); wave w -> rows [p*64+w*8, +8)
    int lrow = lane >> 3, lcol = (lane & 7) * 8;
    const unsigned short* asrc[4];
    const unsigned short* bsrc[4];
#pragma unroll
    for (int p = 0; p < 4; ++p) {
        int gr = row0 + p * 64 + wid * 8 + lrow;
        int ar = rowidx ? rowidx[gr] : gr;
        asrc[p] = A + (size_t)ar * lda + lcol;
        bsrc[p] = Bte + (size_t)(col0 + p * 64 + wid * 8 + lrow) * K + lcol;
    }

    f32x4 acc[8][4] = {};

#define STAGE(buf, k0)                                        \
    {                                                         \
        _Pragma("unroll") for (int p = 0; p < 4; ++p) {       \
            gll16(asrc[p] + (k0), &As[buf][p * 64 + wid * 8][0]); \
            gll16(bsrc[p] + (k0), &Bs[buf][p * 64 + wid * 8][0]); \
        }                                                     \
    }

    STAGE(0, 0);
    __syncthreads();                  // vmcnt(0) drain: tile 0 landed
    int cur = 0;

    for (int t = 0; t < NT2; ++t) {
        if (t + 1 < NT2) STAGE(cur ^ 1, (t + 1) * BK2);   // prefetch BEFORE compute
        __builtin_amdgcn_s_setprio(1);
#pragma unroll
        for (int kk = 0; kk < BK2; kk += 32) {
            bf16x8 af[8], bfr[4];
#pragma unroll
            for (int mi = 0; mi < 8; ++mi)
                af[mi] = *(const bf16x8*)&As[cur][wm * 128 + mi * 16 + l15][kk + l4 * 8];
#pragma unroll
            for (int ni = 0; ni < 4; ++ni)
                bfr[ni] = *(const bf16x8*)&Bs[cur][wn * 64 + ni * 16 + l15][kk + l4 * 8];
#pragma unroll
            for (int mi = 0; mi < 8; ++mi)
#pragma unroll
                for (int ni = 0; ni < 4; ++ni)
                    acc[mi][ni] = __builtin_amdgcn_mfma_f32_16x16x32_bf16(
                        af[mi], bfr[ni], acc[mi][ni], 0, 0, 0);
        }
        __builtin_amdgcn_s_setprio(0);
        __syncthreads();              // reads of tile t done + tile t+1 landed
        cur ^= 1;
    }
#undef STAGE

    float bv[4];
#pragma unroll
    for (int ni = 0; ni < 4; ++ni)
        bv[ni] = bias[col0 + wn * 64 + ni * 16 + l15];

#pragma unroll
    for (int mi = 0; mi < 8; ++mi) {
        int orow_b = row0 + wm * 128 + mi * 16 + l4 * 4;
#pragma unroll
        for (int ni = 0; ni < 4; ++ni) {
            int ocol = col0 + wn * 64 + ni * 16 + l15;
#pragma unroll
            for (int q = 0; q < 4; ++q) {
                size_t oidx = (size_t)(orow_b + q) * N + ocol;
                float v = acc[mi][ni][q] + bv[ni];
                if (VARIANT == 1) {
                    float g = bf2f(Gin[oidx]);
                    float s = g / (1.0f + __expf(-g));
                    v = s * v;
                }
                Out[oidx] = f2bf(v);
            }
        }
    }
}

// ---------------- combine ----------------

__global__ __launch_bounds__(256) void combine_k(
    const unsigned short* __restrict__ Y, const int* __restrict__ rev,
    const float* __restrict__ gates, const int* __restrict__ gidx,
    float* __restrict__ out) {
    int t = blockIdx.x;
    int r0 = rev[2 * t], r1 = rev[2 * t + 1];
    float g0 = gates[gidx[2 * t]], g1 = gates[gidx[2 * t + 1]];
    const unsigned short* y0 = Y + (size_t)r0 * DDIM;
    const unsigned short* y1 = Y + (size_t)r1 * DDIM;
    int d = threadIdx.x * 4;
    ushort4 a = *(const ushort4*)(y0 + d);
    ushort4 b = *(const ushort4*)(y1 + d);
    float4 r;
    r.x = g0 * bf2f(a.x) + g1 * bf2f(b.x);
    r.y = g0 * bf2f(a.y) + g1 * bf2f(b.y);
    r.z = g0 * bf2f(a.z) + g1 * bf2f(b.z);
    r.w = g0 * bf2f(a.w) + g1 * bf2f(b.w);
    *(float4*)(out + (size_t)t * DDIM + d) = r;
}

// ---------------- launch ----------------

extern "C" void kernel_launch(void* const* d_in, const int* in_sizes, int n_in,
                              void* d_out, int out_size, void* d_ws, size_t ws_size,
                              hipStream_t stream) {
    const int* offsets = (const int*)d_in[0];
    const float* jagged = (const float*)d_in[1];
    const float* weight = (const float*)d_in[2];
    const float* bias = (const float*)d_in[3];
    const int* index = (const int*)d_in[4];
    const float* weight_p = (const float*)d_in[5];
    const float* weight_out = (const float*)d_in[6];
    const int* rev = (const int*)d_in[7];
    const float* gates = (const float*)d_in[8];
    const int* gidx = (const int*)d_in[9];
    const float* bias_p = (const float*)d_in[10];
    const float* bias_out = (const float*)d_in[11];
    float* out = (float*)d_out;

    char* w = (char*)d_ws;
    unsigned short* jag_bf = (unsigned short*)w; w += (size_t)T_TOK * DDIM * 2;       // 16MB
    unsigned short* W1t    = (unsigned short*)w; w += (size_t)NEXP * DDIM * HDIM * 2; // 16MB
    unsigned short* Wpt    = (unsigned short*)w; w += (size_t)NEXP * DDIM * HDIM * 2; // 16MB
    unsigned short* Wot    = (unsigned short*)w; w += (size_t)NEXP * HDIM * DDIM * 2; // 16MB
    unsigned short* g_ws   = (unsigned short*)w; w += (size_t)NROWS * HDIM * 2;       // 32MB
    unsigned short* h_ws   = (unsigned short*)w; w += (size_t)NROWS * HDIM * 2;       // 32MB
    unsigned short* y_ws   = g_ws;   // g dead after u-GEMM epilogue; reuse for y

    // prep: bf16 cast + weight transposes (B^T layout)
    cvt_bf16_k<<<(T_TOK * DDIM / 4 + 255) / 256, 256, 0, stream>>>(jagged, jag_bf, T_TOK * DDIM / 4);
    transpose_cast_k<<<dim3(HDIM / 32, DDIM / 32, NEXP), 256, 0, stream>>>(weight, W1t, DDIM, HDIM);
    transpose_cast_k<<<dim3(HDIM / 32, DDIM / 32, NEXP), 256, 0, stream>>>(weight_p, Wpt, DDIM, HDIM);
    transpose_cast_k<<<dim3(DDIM / 32, HDIM / 32, NEXP), 256, 0, stream>>>(weight_out, Wot, HDIM, DDIM);

    const int grid = (NROWS / BM2) * (HDIM / BN2);    // 64 * 4 = 256 blocks

    // g = gather(x) @ W + b
    gemm256_k<0><<<grid, 512, 0, stream>>>(jag_bf, index, DDIM, W1t, bias, nullptr, g_ws,
                                           offsets, HDIM, DDIM);
    // h = silu(g) * (gather(x) @ Wp + bp)
    gemm256_k<1><<<grid, 512, 0, stream>>>(jag_bf, index, DDIM, Wpt, bias_p, g_ws, h_ws,
                                           offsets, HDIM, DDIM);
    // y = h @ Wout + bout
    gemm256_k<0><<<grid, 512, 0, stream>>>(h_ws, nullptr, HDIM, Wot, bias_out, nullptr, y_ws,
                                           offsets, DDIM, HDIM);
    // out[t] = sum_k gates[gidx[t,k]] * y[rev[t,k]]
    combine_k<<<T_TOK, 256, 0, stream>>>(y_ws, rev, gates, gidx, out);
}

// Round 5
// 182.978 us; speedup vs baseline: 1.2651x; 1.1642x over previous
//
#include <hip/hip_runtime.h>
#include <hip/hip_bf16.h>

#define T_TOK 8192
#define DDIM 1024
#define HDIM 1024
#define NEXP 8
#define KTOP 2
#define NROWS (T_TOK * KTOP)

typedef __attribute__((ext_vector_type(8))) short bf16x8;
typedef __attribute__((ext_vector_type(4))) float f32x4;

__device__ __forceinline__ unsigned short f2bf(float f) {
    unsigned u = __builtin_bit_cast(unsigned, f);
    u += 0x7fffu + ((u >> 16) & 1u);   // RNE
    return (unsigned short)(u >> 16);
}
__device__ __forceinline__ float bf2f(unsigned short h) {
    return __builtin_bit_cast(float, (unsigned)h << 16);
}

// async global->LDS, 16B per lane; LDS dest wave-uniform base + lane*16.
__device__ __forceinline__ void gll16(const unsigned short* g, const unsigned short* l) {
    __builtin_amdgcn_global_load_lds(
        (const __attribute__((address_space(1))) unsigned int*)g,
        (__attribute__((address_space(3))) unsigned int*)l, 16, 0, 0);
}

// ---------------- prep kernels ----------------

__global__ __launch_bounds__(256) void cvt_bf16_k(const float* __restrict__ in,
                                                  unsigned short* __restrict__ out, int n4) {
    int i = blockIdx.x * 256 + threadIdx.x;
    if (i >= n4) return;
    float4 v = ((const float4*)in)[i];
    ushort4 o;
    o.x = f2bf(v.x); o.y = f2bf(v.y); o.z = f2bf(v.z); o.w = f2bf(v.w);
    ((ushort4*)out)[i] = o;
}

// in: [nmat][R][C] f32  ->  out: [nmat][C][R] bf16
__global__ __launch_bounds__(256) void transpose_cast_k(const float* __restrict__ in,
                                                        unsigned short* __restrict__ out,
                                                        int R, int C) {
    __shared__ unsigned short tile[32][33];
    int m = blockIdx.z;
    const float* src = in + (size_t)m * R * C;
    unsigned short* dst = out + (size_t)m * R * C;
    int c0 = blockIdx.x * 32, r0 = blockIdx.y * 32;
    int tx = threadIdx.x & 31, ty = threadIdx.x >> 5;
#pragma unroll
    for (int i = 0; i < 32; i += 8)
        tile[ty + i][tx] = f2bf(src[(size_t)(r0 + ty + i) * C + c0 + tx]);
    __syncthreads();
#pragma unroll
    for (int i = 0; i < 32; i += 8)
        dst[(size_t)(c0 + ty + i) * R + r0 + tx] = tile[tx][ty + i];
}

// ---------------- 256x256 GEMM, 8-phase-style deep pipeline (T2+T3+T4+T5) ------
// C = act(A @ Bt^T + bias). 512 thr = 8 waves (2Mx4N), per-wave 128x64 out.
// BK=32, 32 K-tiles, 4 LDS buffers (stage depth 3 tiles), 2 phases/tile
// (mi-half, 16 MFMA each). Counted vmcnt(8) once per tile boundary; never 0
// until the drain tail. Staging: gll16 with linear dest + inverse-swizzled
// global source; reads apply the same XOR (rule 21c) -> 2-way conflicts only.
// LDS swizzle: rows packed 2-per-128B line; 16B-chunk ^= (line&7).
// T1: XCD-chunked block map (XCD x owns expert x's rows).
// VARIANT 0: out = acc + bias ;  VARIANT 1: out = silu(Gin) * (acc + bias)

constexpr int BM2 = 256, BN2 = 256, BK2 = 32;
constexpr int NT2 = DDIM / BK2;   // 32 K-tiles
// LDS byte map: A buf b at b*16384; B buf b at 65536 + b*16384. Total 128 KiB.

template <int VARIANT>
__global__ __launch_bounds__(512) void gemm256_8p_k(
    const unsigned short* __restrict__ A, const int* __restrict__ rowidx, int lda,
    const unsigned short* __restrict__ Bt, const float* __restrict__ biasE,
    const unsigned short* __restrict__ Gin, unsigned short* __restrict__ Out,
    const int* __restrict__ offsets, int N, int K) {
    __shared__ __attribute__((aligned(16))) unsigned short lds[65536];  // 128 KiB

    // XCD-chunked map: 256 blocks, 8 XCDs, 32 each; brow-major within chunk.
    const int nbn = N / BN2;                          // 4
    int l = (blockIdx.x & 7) * 32 + (blockIdx.x >> 3);
    int brow = l / nbn, bcol = l % nbn;
    int row0 = brow * BM2, col0 = bcol * BN2;
    int e = 0;
    while (offsets[e + 1] <= row0) ++e;

    const unsigned short* Bte = Bt + (size_t)e * N * K;
    const float* bias = biasE + (size_t)e * N;

    int tid = threadIdx.x;
    int lane = tid & 63, wid = tid >> 6;
    int wm = wid >> 2, wn = wid & 3;                  // 2x4 wave grid
    int l15 = lane & 15, l4 = lane >> 4;

    // ---- staging source mapping (inverse of LDS swizzle; rule 21c) ----
    // Linear LDS slot of lane i (within a 1024B group of 8 lines): line=i>>3,
    // phys chunk=i&7. That slot logically holds chunk c=(i&7)^(i>>3) of
    // row pair: row = 2*(i>>3) + (c>>2), 16B col (c&3).
    int sc = (lane & 7) ^ (lane >> 3);
    int srow = ((lane >> 3) << 1) + (sc >> 2);        // 0..15 within group
    int scol = (sc & 3) * 8;                          // bf16 elems
    const unsigned short* asrc[2];
    const unsigned short* bsrc[2];
#pragma unroll
    for (int q = 0; q < 2; ++q) {
        int gr = row0 + (wid * 2 + q) * 16 + srow;
        int ar = rowidx ? rowidx[gr] : gr;
        asrc[q] = A + (size_t)ar * lda + scol;
        bsrc[q] = Bte + (size_t)(col0 + (wid * 2 + q) * 16 + srow) * K + scol;
    }
    // wave-uniform LDS dest bases (ushort units; 1024B group per (wave,q))
    unsigned adst[2], bdst[2];
#pragma unroll
    for (int q = 0; q < 2; ++q) {
        adst[q] = (wid * 2 + q) * 512;
        bdst[q] = 32768 + (wid * 2 + q) * 512;
    }

#define STAGE_A(t) { int _b = (t) & 3; int _k = (t) * BK2;            \
        gll16(asrc[0] + _k, lds + _b * 8192 + adst[0]);               \
        gll16(asrc[1] + _k, lds + _b * 8192 + adst[1]); }
#define STAGE_B(t) { int _b = (t) & 3; int _k = (t) * BK2;            \
        gll16(bsrc[0] + _k, lds + _b * 8192 + bdst[0]);               \
        gll16(bsrc[1] + _k, lds + _b * 8192 + bdst[1]); }

    // ---- swizzled read offset (bytes within a line group) ----
    // row = base + l15 (base mult of 16): line&7 = l15>>1; chunk = ((row&1)<<2)|l4
    int rdoff = (l15 >> 1) * 128 + ((((l15 & 1) << 2) | l4) ^ (l15 >> 1)) * 16;

    f32x4 acc[8][4] = {};

    // prologue: stage tiles 0,1,2 (depth 3), drain tile 0 (8 = tiles 1,2 in flight)
    STAGE_A(0) STAGE_B(0) STAGE_A(1) STAGE_B(1) STAGE_A(2) STAGE_B(2)
    asm volatile("s_waitcnt vmcnt(8)" ::: "memory");
    __builtin_amdgcn_s_barrier();

#pragma unroll 1
    for (int t = 0; t < NT2; ++t) {
        const char* Ab = (const char*)lds + (t & 3) * 16384;
        const char* Bb = (const char*)lds + 65536 + (t & 3) * 16384;
        bf16x8 af0[4], af1[4], bfr[4];

        // ---- even phase: A-half0 + B frags; stage A(t+3) ----
#pragma unroll
        for (int mi = 0; mi < 4; ++mi)
            af0[mi] = *(const bf16x8*)(Ab + (wm * 64 + mi * 8) * 128 + rdoff);
#pragma unroll
        for (int ni = 0; ni < 4; ++ni)
            bfr[ni] = *(const bf16x8*)(Bb + (wn * 32 + ni * 8) * 128 + rdoff);
        if (t + 3 < NT2) STAGE_A(t + 3)
        __builtin_amdgcn_s_barrier();
        asm volatile("s_waitcnt lgkmcnt(0)" ::: "memory");
        __builtin_amdgcn_sched_barrier(0);
        __builtin_amdgcn_s_setprio(1);
#pragma unroll
        for (int mi = 0; mi < 4; ++mi)
#pragma unroll
            for (int ni = 0; ni < 4; ++ni)
                acc[mi][ni] = __builtin_amdgcn_mfma_f32_16x16x32_bf16(
                    af0[mi], bfr[ni], acc[mi][ni], 0, 0, 0);
        __builtin_amdgcn_s_setprio(0);
        __builtin_amdgcn_s_barrier();

        // ---- odd phase: A-half1 (B reused in regs); stage B(t+3) ----
#pragma unroll
        for (int mi = 0; mi < 4; ++mi)
            af1[mi] = *(const bf16x8*)(Ab + (wm * 64 + 32 + mi * 8) * 128 + rdoff);
        if (t + 3 < NT2) STAGE_B(t + 3)
        __builtin_amdgcn_s_barrier();
        asm volatile("s_waitcnt lgkmcnt(0)" ::: "memory");
        __builtin_amdgcn_sched_barrier(0);
        __builtin_amdgcn_s_setprio(1);
#pragma unroll
        for (int mi = 0; mi < 4; ++mi)
#pragma unroll
            for (int ni = 0; ni < 4; ++ni)
                acc[4 + mi][ni] = __builtin_amdgcn_mfma_f32_16x16x32_bf16(
                    af1[mi], bfr[ni], acc[4 + mi][ni], 0, 0, 0);
        __builtin_amdgcn_s_setprio(0);

        // ---- tile boundary: counted vmcnt (tile t+1 must be landed) ----
        if (t < NT2 - 1) {
            if (t <= NT2 - 4)      asm volatile("s_waitcnt vmcnt(8)" ::: "memory");
            else if (t == NT2 - 3) asm volatile("s_waitcnt vmcnt(4)" ::: "memory");
            else                   asm volatile("s_waitcnt vmcnt(0)" ::: "memory");
            __builtin_amdgcn_s_barrier();
        }
    }
#undef STAGE_A
#undef STAGE_B

    float bv[4];
#pragma unroll
    for (int ni = 0; ni < 4; ++ni)
        bv[ni] = bias[col0 + wn * 64 + ni * 16 + l15];

#pragma unroll
    for (int a = 0; a < 8; ++a) {
        int orow_b = row0 + wm * 128 + (a >> 2) * 64 + (a & 3) * 16 + l4 * 4;
#pragma unroll
        for (int ni = 0; ni < 4; ++ni) {
            int ocol = col0 + wn * 64 + ni * 16 + l15;
#pragma unroll
            for (int q = 0; q < 4; ++q) {
                size_t oidx = (size_t)(orow_b + q) * N + ocol;
                float v = acc[a][ni][q] + bv[ni];
                if (VARIANT == 1) {
                    float g = bf2f(Gin[oidx]);
                    float s = g / (1.0f + __expf(-g));
                    v = s * v;
                }
                Out[oidx] = f2bf(v);
            }
        }
    }
}

// ---------------- combine ----------------

__global__ __launch_bounds__(256) void combine_k(
    const unsigned short* __restrict__ Y, const int* __restrict__ rev,
    const float* __restrict__ gates, const int* __restrict__ gidx,
    float* __restrict__ out) {
    int t = blockIdx.x;
    int r0 = rev[2 * t], r1 = rev[2 * t + 1];
    float g0 = gates[gidx[2 * t]], g1 = gates[gidx[2 * t + 1]];
    const unsigned short* y0 = Y + (size_t)r0 * DDIM;
    const unsigned short* y1 = Y + (size_t)r1 * DDIM;
    int d = threadIdx.x * 4;
    ushort4 a = *(const ushort4*)(y0 + d);
    ushort4 b = *(const ushort4*)(y1 + d);
    float4 r;
    r.x = g0 * bf2f(a.x) + g1 * bf2f(b.x);
    r.y = g0 * bf2f(a.y) + g1 * bf2f(b.y);
    r.z = g0 * bf2f(a.z) + g1 * bf2f(b.z);
    r.w = g0 * bf2f(a.w) + g1 * bf2f(b.w);
    *(float4*)(out + (size_t)t * DDIM + d) = r;
}

// ---------------- launch ----------------

extern "C" void kernel_launch(void* const* d_in, const int* in_sizes, int n_in,
                              void* d_out, int out_size, void* d_ws, size_t ws_size,
                              hipStream_t stream) {
    const int* offsets = (const int*)d_in[0];
    const float* jagged = (const float*)d_in[1];
    const float* weight = (const float*)d_in[2];
    const float* bias = (const float*)d_in[3];
    const int* index = (const int*)d_in[4];
    const float* weight_p = (const float*)d_in[5];
    const float* weight_out = (const float*)d_in[6];
    const int* rev = (const int*)d_in[7];
    const float* gates = (const float*)d_in[8];
    const int* gidx = (const int*)d_in[9];
    const float* bias_p = (const float*)d_in[10];
    const float* bias_out = (const float*)d_in[11];
    float* out = (float*)d_out;

    char* w = (char*)d_ws;
    unsigned short* jag_bf = (unsigned short*)w; w += (size_t)T_TOK * DDIM * 2;       // 16MB
    unsigned short* W1t    = (unsigned short*)w; w += (size_t)NEXP * DDIM * HDIM * 2; // 16MB
    unsigned short* Wpt    = (unsigned short*)w; w += (size_t)NEXP * DDIM * HDIM * 2; // 16MB
    unsigned short* Wot    = (unsigned short*)w; w += (size_t)NEXP * HDIM * DDIM * 2; // 16MB
    unsigned short* g_ws   = (unsigned short*)w; w += (size_t)NROWS * HDIM * 2;       // 32MB
    unsigned short* h_ws   = (unsigned short*)w; w += (size_t)NROWS * HDIM * 2;       // 32MB
    unsigned short* y_ws   = g_ws;   // g dead after u-GEMM epilogue; reuse for y

    // prep: bf16 cast + weight transposes (B^T layout)
    cvt_bf16_k<<<(T_TOK * DDIM / 4 + 255) / 256, 256, 0, stream>>>(jagged, jag_bf, T_TOK * DDIM / 4);
    transpose_cast_k<<<dim3(HDIM / 32, DDIM / 32, NEXP), 256, 0, stream>>>(weight, W1t, DDIM, HDIM);
    transpose_cast_k<<<dim3(HDIM / 32, DDIM / 32, NEXP), 256, 0, stream>>>(weight_p, Wpt, DDIM, HDIM);
    transpose_cast_k<<<dim3(DDIM / 32, HDIM / 32, NEXP), 256, 0, stream>>>(weight_out, Wot, HDIM, DDIM);

    const int grid = (NROWS / BM2) * (HDIM / BN2);    // 64 * 4 = 256 blocks

    // g = gather(x) @ W + b
    gemm256_8p_k<0><<<grid, 512, 0, stream>>>(jag_bf, index, DDIM, W1t, bias, nullptr, g_ws,
                                              offsets, HDIM, DDIM);
    // h = silu(g) * (gather(x) @ Wp + bp)
    gemm256_8p_k<1><<<grid, 512, 0, stream>>>(jag_bf, index, DDIM, Wpt, bias_p, g_ws, h_ws,
                                              offsets, HDIM, DDIM);
    // y = h @ Wout + bout
    gemm256_8p_k<0><<<grid, 512, 0, stream>>>(h_ws, nullptr, HDIM, Wot, bias_out, nullptr, y_ws,
                                              offsets, DDIM, HDIM);
    // out[t] = sum_k gates[gidx[t,k]] * y[rev[t,k]]
    combine_k<<<T_TOK, 256, 0, stream>>>(y_ws, rev, gates, gidx, out);
}